// Round 8
// baseline (382.080 us; speedup 1.0000x reference)
//
#include <hip/hip_runtime.h>

typedef unsigned short u16;
typedef u16   u16x4  __attribute__((ext_vector_type(4)));
typedef u16   u16x8  __attribute__((ext_vector_type(8)));
typedef __bf16 bf16x8 __attribute__((ext_vector_type(8)));
typedef float f32x4  __attribute__((ext_vector_type(4)));

constexpr int BATCH  = 4;
constexpr int CDIM   = 256;
constexpr int NTOK   = 16384;   // 128*128
constexpr int INNERD = 512;

// native bf16 converts (v_cvt_pk_bf16_f32, RNE)
__device__ __forceinline__ u16 f2b(float f) {
  return __builtin_bit_cast(u16, (__bf16)f);
}
__device__ __forceinline__ float b2f(u16 b) {
  return (float)__builtin_bit_cast(__bf16, b);
}

// async global->LDS, 16B per lane. LDS dest must be WAVE-UNIFORM base;
// HW writes lane i's data at base + i*16. Global src is per-lane.
__device__ __forceinline__ void async_ld16(const u16* g, u16* l) {
  __builtin_amdgcn_global_load_lds(
      (const __attribute__((address_space(1))) void*)g,
      (__attribute__((address_space(3))) void*)l, 16, 0, 0);
}

// ---------------- prep: transpose_cvt + wtrans + zero fused (launch saving) ----
// id [0,16384): transpose (b,c,n) f32 -> (b,n,c) bf16 for x and ctx
// id [16384,16768): weight transpose (256,512) f32 -> (512,256) bf16
// id [16768,17288): zero cm/ksum scratch
constexpr int ZERO_N = BATCH * 8 * 64 * 64 + BATCH * INNERD;  // 133120
__global__ __launch_bounds__(256) void prep(
    const float* __restrict__ x, const float* __restrict__ ctx,
    const float* __restrict__ Wq, const float* __restrict__ Wk, const float* __restrict__ Wv,
    u16* __restrict__ xt, u16* __restrict__ ct,
    u16* __restrict__ qt, u16* __restrict__ kt, u16* __restrict__ vt,
    float* __restrict__ zbuf) {
  __shared__ float tile[64][33];   // reused by both transpose branches
  int id = blockIdx.x;
  if (id < 16384) {
    int bx = id & 511, by = (id >> 9) & 3, zb = id >> 11;
    int b = zb >> 1;
    const float* src = (zb & 1) ? ctx : x;
    u16* dst = (zb & 1) ? ct : xt;
    src += (size_t)b * CDIM * NTOK;
    dst += (size_t)b * NTOK * CDIM;
    int n0 = bx * 32, c0 = by * 64;
    int tx = threadIdx.x & 31, ty = threadIdx.x >> 5;   // ty 0..7
#pragma unroll
    for (int i = 0; i < 64; i += 8)
      tile[ty + i][tx] = src[(size_t)(c0 + ty + i) * NTOK + n0 + tx];
    __syncthreads();
    int nl = threadIdx.x >> 3;          // 0..31
    int cl = (threadIdx.x & 7) * 8;     // 0..56
    u16x8 o;
#pragma unroll
    for (int j = 0; j < 8; j++) o[j] = f2b(tile[cl + j][nl]);
    *(u16x8*)&dst[(size_t)(n0 + nl) * CDIM + c0 + cl] = o;
  } else if (id < 16768) {
    int idw = id - 16384;
    int bx = idw & 15, by = (idw >> 4) & 7, bz = idw >> 7;  // 16 x 8 x 3
    float (*t2)[33] = (float(*)[33])tile;
    const float* src = bz == 0 ? Wq : (bz == 1 ? Wk : Wv);
    u16* dst = bz == 0 ? qt : (bz == 1 ? kt : vt);
    int i0 = bx * 32, c0 = by * 32;
    int tx = threadIdx.x & 31, ty = threadIdx.x >> 5;
#pragma unroll
    for (int r = 0; r < 32; r += 8)
      t2[ty + r][tx] = src[(size_t)(c0 + ty + r) * INNERD + i0 + tx];
    __syncthreads();
#pragma unroll
    for (int r = 0; r < 32; r += 8)
      dst[(size_t)(i0 + ty + r) * CDIM + c0 + tx] = f2b(t2[tx][ty + r]);
  } else {
    int i = (id - 16768) * 256 + threadIdx.x;
    if (i < ZERO_N) zbuf[i] = 0.0f;
  }
}

// ================= fused projection + context matrix (T4 counted-vmcnt) ========
// Per block: b, i-range 128 (heads ig*2, ig*2+1), n-chunk 512.
// GEMM loop uses 3 staging bufs + raw s_barrier + s_waitcnt vmcnt(4): stage(s+1)
// stays IN FLIGHT across the barrier (never drained to 0 in steady state, T4).
// Each wave's wait covers its own loads; barrier makes it collective.
__global__ __launch_bounds__(256, 2) void proj_ctx(
    const u16* __restrict__ Wkt, const u16* __restrict__ Wvt,
    const u16* __restrict__ ctx_bt, float* __restrict__ cm, float* __restrict__ ksum) {
  // 512 blocks = 4(ig) x 32(nc) x 4(b); chunked XCD swizzle
  int id = blockIdx.x;
  int swz = (id & 7) * 64 + (id >> 3);
  int ig = swz & 3, nc = (swz >> 2) & 31, b = swz >> 7;
  int i0 = ig * 128;
  const u16* Bt = ctx_bt + (size_t)b * NTOK * CDIM;

  __shared__ __align__(16) u16 smem[40960];   // 80 KiB -> 2 blocks/CU
  // staging buf p (p=0,1,2) at p*8192 u16 (16 KiB each): A 4096 u16 + B 4096 u16
  u16* Ek = smem + 24576;    // [48K,80K) expK tile, dedicated
  u16* Vt = smem;            // [0,32K)   V tile, aliases bufs 0,1

  int tid = threadIdx.x, wave = tid >> 6, lane = tid & 63;
  int wm = (wave >> 1) * 64, wn = (wave & 1) * 64;
  int quad = lane >> 4, l16 = lane & 15;
  int sr = lane >> 2, sc = (lane & 3) * 8;      // staging: 16 rows x 32 cols/chunk

  int hl = wave >> 1, dblk = (wave & 1) * 32;   // phase-2: wave -> (head, d-half)

  u16x8 ov;
#pragma unroll
  for (int t = 0; t < 8; t++) ov[t] = 0x3f80;   // bf16 1.0
  const bf16x8 ones = __builtin_bit_cast(bf16x8, ov);

  f32x4 acc_cm[2][4];
  f32x4 accS[2];
#pragma unroll
  for (int i = 0; i < 2; i++) {
    accS[i] = (f32x4)(0.0f);
#pragma unroll
    for (int j = 0; j < 4; j++) acc_cm[i][j] = (f32x4)(0.0f);
  }

  // stage step (kv = s>>3, k-slice = s&7) into buf p. 16 chunks; 4 loads/wave.
  auto stage = [&](int p, int s, int n0) {
    int k0 = (s & 7) * 32;
    const u16* Asrc = (s & 8) ? Wvt : Wkt;
#pragma unroll
    for (int j = 0; j < 4; j++) {
      int c = wave * 4 + j;            // 0..15
      if (c < 8) {
        int row = c * 16 + sr;
        async_ld16(&Asrc[(size_t)(i0 + row) * CDIM + k0 + sc], &smem[p * 8192 + c * 512]);
      } else {
        int cb = c - 8, row = cb * 16 + sr;
        async_ld16(&Bt[(size_t)(n0 + row) * CDIM + k0 + sc], &smem[p * 8192 + 4096 + cb * 512]);
      }
    }
  };

  for (int nt = 0; nt < 4; nt++) {
    int n0 = nc * 512 + nt * 128;
    __syncthreads();                   // phase-2 reads of Vt/Ek done (or block start)
    stage(0, 0, n0);
    stage(1, 1, n0);

    f32x4 acc[4][4];
#pragma unroll
    for (int i = 0; i < 4; i++)
#pragma unroll
      for (int j = 0; j < 4; j++) acc[i][j] = (f32x4)(0.0f);

#pragma unroll 2
    for (int s = 0; s < 16; s++) {     // s>>3 = kv, s&7 = k-slice
      // readiness: my stage(s) loads done; stage(s+1) stays in flight (T4)
      if (s < 15) asm volatile("s_waitcnt vmcnt(4)" ::: "memory");
      else        asm volatile("s_waitcnt vmcnt(0)" ::: "memory");
      __builtin_amdgcn_s_barrier();    // raw: no compiler vmcnt(0) drain
      __builtin_amdgcn_sched_barrier(0);

      int p = s % 3;
      const u16* As = &smem[p * 8192];
      const u16* Bs = &smem[p * 8192 + 4096];
      bf16x8 af[4], bfr[4];
#pragma unroll
      for (int m = 0; m < 4; m++)
        af[m] = __builtin_bit_cast(bf16x8, *(const u16x8*)&As[(wm + m * 16 + l16) * 32 + quad * 8]);
#pragma unroll
      for (int e = 0; e < 4; e++)
        bfr[e] = __builtin_bit_cast(bf16x8, *(const u16x8*)&Bs[(wn + e * 16 + l16) * 32 + quad * 8]);
      // swapped operands: lane holds 4 consecutive n per frag
#pragma unroll
      for (int e = 0; e < 4; e++)
#pragma unroll
        for (int m = 0; m < 4; m++)
          acc[e][m] = __builtin_amdgcn_mfma_f32_16x16x32_bf16(bfr[e], af[m], acc[e][m], 0, 0, 0);

      if (s == 7) {
        // K-GEMM complete: write exp(K) to dedicated Ek (XOR-swz), reset acc for V
#pragma unroll
        for (int e = 0; e < 4; e++) {
          int nl0 = wn + e * 16 + quad * 4;
#pragma unroll
          for (int m = 0; m < 4; m++) {
            int row = wm + m * 16 + l16;
            u16x4 ok;
#pragma unroll
            for (int r = 0; r < 4; r++) ok[r] = f2b(__expf(acc[e][m][r]));
            unsigned byt = (unsigned)(row * 256 + nl0 * 2) ^ ((unsigned)(row & 7) << 4);
            *(u16x4*)((char*)Ek + byt) = ok;
            acc[e][m] = (f32x4)(0.0f);
          }
        }
      }
      // issue next+1 stage: buf (s+2)%3 == (s-1)%3, whose readers all passed
      // barrier(s) -> safe. Keeps 8 loads in flight, never drained mid-loop.
      if (s < 14) stage((s + 2) % 3, s + 2, n0);
    }
    __syncthreads();                   // all waves' buf reads done (Vt aliases bufs)
    // acc holds V tile
#pragma unroll
    for (int e = 0; e < 4; e++) {
      int nl0 = wn + e * 16 + quad * 4;
#pragma unroll
      for (int m = 0; m < 4; m++) {
        int row = wm + m * 16 + l16;
        u16x4 ovv;
#pragma unroll
        for (int r = 0; r < 4; r++) ovv[r] = f2b(acc[e][m][r]);
        unsigned byt = (unsigned)(row * 256 + nl0 * 2) ^ ((unsigned)(row & 7) << 4);
        *(u16x4*)((char*)Vt + byt) = ovv;
      }
    }
    __syncthreads();                   // Ek/Vt visible to all waves (lgkm drained)
    // phase 2: per wave (hl, dblk): acc_cm[m2][e2] += Ek_row · Vt_row over 128 n
#pragma unroll
    for (int kk = 0; kk < 128; kk += 32) {
      int ko = kk + quad * 8;
      bf16x8 ea[2], vb[4];
#pragma unroll
      for (int m2 = 0; m2 < 2; m2++) {
        int row = hl * 64 + dblk + m2 * 16 + l16;
        unsigned byt = (unsigned)(row * 256 + ko * 2) ^ ((unsigned)(row & 7) << 4);
        ea[m2] = __builtin_bit_cast(bf16x8, *(const u16x8*)((char*)Ek + byt));
      }
#pragma unroll
      for (int e2 = 0; e2 < 4; e2++) {
        int row = hl * 64 + e2 * 16 + l16;
        unsigned byt = (unsigned)(row * 256 + ko * 2) ^ ((unsigned)(row & 7) << 4);
        vb[e2] = __builtin_bit_cast(bf16x8, *(const u16x8*)((char*)Vt + byt));
      }
#pragma unroll
      for (int m2 = 0; m2 < 2; m2++) {
        accS[m2] = __builtin_amdgcn_mfma_f32_16x16x32_bf16(ea[m2], ones, accS[m2], 0, 0, 0);
#pragma unroll
        for (int e2 = 0; e2 < 4; e2++)
          acc_cm[m2][e2] = __builtin_amdgcn_mfma_f32_16x16x32_bf16(ea[m2], vb[e2], acc_cm[m2][e2], 0, 0, 0);
      }
    }
    // next nt's first __syncthreads protects Ek/Vt vs staging overwrite
  }
  // epilogue: waves own disjoint (h, d-half) -> no intra-block contention
  int h = ig * 2 + hl;
  float* cmp = cm + (size_t)(b * 8 + h) * 64 * 64;
#pragma unroll
  for (int m2 = 0; m2 < 2; m2++)
#pragma unroll
    for (int e2 = 0; e2 < 4; e2++)
#pragma unroll
      for (int r = 0; r < 4; r++) {
        int d = dblk + m2 * 16 + quad * 4 + r;
        int e = e2 * 16 + l16;
        atomicAdd(&cmp[d * 64 + e], acc_cm[m2][e2][r]);
      }
  if (l16 == 0) {
#pragma unroll
    for (int m2 = 0; m2 < 2; m2++)
#pragma unroll
      for (int r = 0; r < 4; r++) {
        int d = dblk + m2 * 16 + quad * 4 + r;
        atomicAdd(&ksum[(size_t)b * INNERD + h * 64 + d], accS[m2][r]);
      }
  }
}

// ---------------- weff[b][i=h*64+d][c] = (sum_e cm[d][e]*Wo[h*64+e][c])/ksum ---
__global__ __launch_bounds__(256) void weff_k(
    const float* __restrict__ cm, const float* __restrict__ Wo,
    const float* __restrict__ ksum, float* __restrict__ weff) {
  int bi = blockIdx.x;            // 0..2047
  int b = bi >> 9, i = bi & 511, h = i >> 6, d = i & 63;
  const float* cmr = cm + ((size_t)(b * 8 + h) * 64 + d) * 64;
  __shared__ float cs[64];
  if (threadIdx.x < 64) cs[threadIdx.x] = cmr[threadIdx.x];
  __syncthreads();
  float inv = 1.0f / ksum[(size_t)b * INNERD + i];
  int c = threadIdx.x;
  float s = 0.0f;
#pragma unroll 8
  for (int e = 0; e < 64; e++) s += cs[e] * Wo[(size_t)(h * 64 + e) * CDIM + c];
  weff[(size_t)bi * CDIM + c] = s * inv;
}

// ---------------- Gt[b][c][c'] = sum_i weff[b][i][c] * Wq_t[i][c']  (bf16) -----
__global__ __launch_bounds__(256) void gt_k(
    const float* __restrict__ weff, const u16* __restrict__ Wq_t, u16* __restrict__ Gt) {
  int bc = blockIdx.x;            // 0..1023
  int b = bc >> 8, c = bc & 255;
  __shared__ float ws[512];
  for (int j = threadIdx.x; j < 512; j += 256)
    ws[j] = weff[((size_t)b * 512 + j) * CDIM + c];
  __syncthreads();
  int cp = threadIdx.x;
  float s = 0.0f;
#pragma unroll 8
  for (int i = 0; i < 512; i++) s += ws[i] * b2f(Wq_t[(size_t)i * CDIM + cp]);
  Gt[(size_t)bc * CDIM + cp] = f2b(s);
}

// ---------------- final: out[b][c][n] = x + bo[c] + sum_c' Gt[c][c'] x_bt[n][c']
// Prefetch ladder (BK=32, 8 steps); f32x4 residual epilogue.
__global__ __launch_bounds__(256) void final_gemm(
    const u16* __restrict__ Gt, const u16* __restrict__ x_bt,
    const float* __restrict__ x, const float* __restrict__ bo,
    float* __restrict__ out) {
  // flattened grid 1024 = 2(x) * 128(y) * 4(z); chunked XCD swizzle
  int id = blockIdx.x;
  int swz = (id & 7) * 128 + (id >> 3);
  int bx = swz & 1, by = (swz >> 1) & 127, b = swz >> 8;
  const u16* A  = Gt + (size_t)b * CDIM * CDIM;
  const u16* Bt = x_bt + (size_t)b * NTOK * CDIM;
  const float* xb = x + (size_t)b * CDIM * NTOK;
  float* ob = out + (size_t)b * CDIM * NTOK;
  int i0 = bx * 128;
  int n0 = by * 128;

  __shared__ __align__(16) u16 smem2[16384];   // 32 KiB: 2 bufs x (A 4K + B 4K u16)

  int tid = threadIdx.x;
  int wave = tid >> 6, lane = tid & 63;
  int wm = (wave >> 1) * 64, wn = (wave & 1) * 64;
  int quad = lane >> 4, l16 = lane & 15;
  int sr = lane >> 2, sc = (lane & 3) * 8;

  auto stage = [&](int p, int ks) {
    int k0 = ks * 32;
#pragma unroll
    for (int j = 0; j < 4; j++) {
      int c = wave * 4 + j;
      if (c < 8) {
        int row = c * 16 + sr;
        async_ld16(&A[(size_t)(i0 + row) * CDIM + k0 + sc], &smem2[p * 8192 + c * 512]);
      } else {
        int cb = c - 8, row = cb * 16 + sr;
        async_ld16(&Bt[(size_t)(n0 + row) * CDIM + k0 + sc], &smem2[p * 8192 + 4096 + cb * 512]);
      }
    }
  };

  f32x4 acc[4][4];   // [e:n-frag][m:c-frag]
#pragma unroll
  for (int i = 0; i < 4; i++)
#pragma unroll
    for (int j = 0; j < 4; j++) acc[i][j] = (f32x4)(0.0f);

  stage(0, 0);
  __syncthreads();
#pragma unroll 2
  for (int s = 0; s < 8; s++) {
    int p = s & 1;
    if (s < 7) stage(p ^ 1, s + 1);
    const u16* As = &smem2[p * 8192];
    const u16* Bs = &smem2[p * 8192 + 4096];
    bf16x8 af[4], bfr[4];
#pragma unroll
    for (int m = 0; m < 4; m++)
      af[m] = __builtin_bit_cast(bf16x8, *(const u16x8*)&As[(wm + m * 16 + l16) * 32 + quad * 8]);
#pragma unroll
    for (int e = 0; e < 4; e++)
      bfr[e] = __builtin_bit_cast(bf16x8, *(const u16x8*)&Bs[(wn + e * 16 + l16) * 32 + quad * 8]);
#pragma unroll
    for (int e = 0; e < 4; e++)
#pragma unroll
      for (int m = 0; m < 4; m++)
        acc[e][m] = __builtin_amdgcn_mfma_f32_16x16x32_bf16(bfr[e], af[m], acc[e][m], 0, 0, 0);
    if (s < 7) __syncthreads();
  }
  // lane's acc[e][m][r]: c = i0+wm+m*16+l16, n = n0+wn+e*16+quad*4+r
#pragma unroll
  for (int e = 0; e < 4; e++) {
    int nb = n0 + wn + e * 16 + quad * 4;
#pragma unroll
    for (int m = 0; m < 4; m++) {
      int c = i0 + wm + m * 16 + l16;
      f32x4 xv = *(const f32x4*)&xb[(size_t)c * NTOK + nb];
      f32x4 r;
      float bc = bo[c];
#pragma unroll
      for (int t = 0; t < 4; t++) r[t] = acc[e][m][t] + xv[t] + bc;
      *(f32x4*)&ob[(size_t)c * NTOK + nb] = r;
    }
  }
}

extern "C" void kernel_launch(void* const* d_in, const int* in_sizes, int n_in,
                              void* d_out, int out_size, void* d_ws, size_t ws_size,
                              hipStream_t stream) {
  const float* x   = (const float*)d_in[0];
  const float* ctx = (const float*)d_in[1];
  const float* Wq  = (const float*)d_in[2];
  const float* Wk  = (const float*)d_in[3];
  const float* Wv  = (const float*)d_in[4];
  const float* Wo  = (const float*)d_in[5];
  const float* bo  = (const float*)d_in[6];
  float* out = (float*)d_out;

  char* ws = (char*)d_ws;
  u16* ctx_bt = (u16*)ws;  ws += (size_t)BATCH * NTOK * CDIM * 2;     // 32 MiB
  u16* x_bt   = (u16*)ws;  ws += (size_t)BATCH * NTOK * CDIM * 2;     // 32 MiB
  u16* Wq_t   = (u16*)ws;  ws += (size_t)INNERD * CDIM * 2;
  u16* Wk_t   = (u16*)ws;  ws += (size_t)INNERD * CDIM * 2;
  u16* Wv_t   = (u16*)ws;  ws += (size_t)INNERD * CDIM * 2;
  float* cm   = (float*)ws; ws += (size_t)BATCH * 8 * 64 * 64 * 4;    // 512 KiB
  float* ksum = (float*)ws; ws += (size_t)BATCH * INNERD * 4;         // 8 KiB (contiguous after cm)
  float* weff = (float*)ws; ws += (size_t)BATCH * INNERD * CDIM * 4;  // 2 MiB
  u16* Gt     = (u16*)ws;  ws += (size_t)BATCH * CDIM * CDIM * 2;

  prep<<<dim3(17288), 256, 0, stream>>>(x, ctx, Wq, Wk, Wv, x_bt, ctx_bt,
                                        Wq_t, Wk_t, Wv_t, cm /* zero cm+ksum */);
  proj_ctx<<<dim3(512), 256, 0, stream>>>(Wk_t, Wv_t, ctx_bt, cm, ksum);
  weff_k<<<BATCH * INNERD, 256, 0, stream>>>(cm, Wo, ksum, weff);
  gt_k<<<BATCH * CDIM, 256, 0, stream>>>(weff, Wq_t, Gt);
  final_gemm<<<dim3(1024), 256, 0, stream>>>(Gt, x_bt, x, bo, out);
}

// Round 9
// 342.516 us; speedup vs baseline: 1.1155x; 1.1155x over previous
//
#include <hip/hip_runtime.h>

typedef unsigned short u16;
typedef u16   u16x4  __attribute__((ext_vector_type(4)));
typedef u16   u16x8  __attribute__((ext_vector_type(8)));
typedef __bf16 bf16x8 __attribute__((ext_vector_type(8)));
typedef float f32x4  __attribute__((ext_vector_type(4)));

constexpr int BATCH  = 4;
constexpr int CDIM   = 256;
constexpr int NTOK   = 16384;   // 128*128
constexpr int INNERD = 512;

// native bf16 converts (v_cvt_pk_bf16_f32, RNE)
__device__ __forceinline__ u16 f2b(float f) {
  return __builtin_bit_cast(u16, (__bf16)f);
}
__device__ __forceinline__ float b2f(u16 b) {
  return (float)__builtin_bit_cast(__bf16, b);
}

// async global->LDS, 16B per lane. LDS dest must be WAVE-UNIFORM base;
// HW writes lane i's data at base + i*16. Global src is per-lane.
__device__ __forceinline__ void async_ld16(const u16* g, u16* l) {
  __builtin_amdgcn_global_load_lds(
      (const __attribute__((address_space(1))) void*)g,
      (__attribute__((address_space(3))) void*)l, 16, 0, 0);
}

// ---------------- prep: transpose_cvt + wtrans(K,V only) + zero fused ----------
// id [0,16384): transpose (b,c,n) f32 -> (b,n,c) bf16 for x and ctx
// id [16384,16640): weight transpose (256,512) f32 -> (512,256) bf16 for Wk,Wv
// id [16640,17160): zero cm/ksum scratch
constexpr int ZERO_N = BATCH * 8 * 64 * 64 + BATCH * INNERD;  // 133120
__global__ __launch_bounds__(256) void prep(
    const float* __restrict__ x, const float* __restrict__ ctx,
    const float* __restrict__ Wk, const float* __restrict__ Wv,
    u16* __restrict__ xt, u16* __restrict__ ct,
    u16* __restrict__ kt, u16* __restrict__ vt,
    float* __restrict__ zbuf) {
  __shared__ float tile[64][33];   // reused by both transpose branches
  int id = blockIdx.x;
  if (id < 16384) {
    int bx = id & 511, by = (id >> 9) & 3, zb = id >> 11;
    int b = zb >> 1;
    const float* src = (zb & 1) ? ctx : x;
    u16* dst = (zb & 1) ? ct : xt;
    src += (size_t)b * CDIM * NTOK;
    dst += (size_t)b * NTOK * CDIM;
    int n0 = bx * 32, c0 = by * 64;
    int tx = threadIdx.x & 31, ty = threadIdx.x >> 5;   // ty 0..7
#pragma unroll
    for (int i = 0; i < 64; i += 8)
      tile[ty + i][tx] = src[(size_t)(c0 + ty + i) * NTOK + n0 + tx];
    __syncthreads();
    int nl = threadIdx.x >> 3;          // 0..31
    int cl = (threadIdx.x & 7) * 8;     // 0..56
    u16x8 o;
#pragma unroll
    for (int j = 0; j < 8; j++) o[j] = f2b(tile[cl + j][nl]);
    *(u16x8*)&dst[(size_t)(n0 + nl) * CDIM + c0 + cl] = o;
  } else if (id < 16640) {
    int idw = id - 16384;
    int bx = idw & 15, by = (idw >> 4) & 7, bz = idw >> 7;  // 16 x 8 x 2
    float (*t2)[33] = (float(*)[33])tile;
    const float* src = bz == 0 ? Wk : Wv;
    u16* dst = bz == 0 ? kt : vt;
    int i0 = bx * 32, c0 = by * 32;
    int tx = threadIdx.x & 31, ty = threadIdx.x >> 5;
#pragma unroll
    for (int r = 0; r < 32; r += 8)
      t2[ty + r][tx] = src[(size_t)(c0 + ty + r) * INNERD + i0 + tx];
    __syncthreads();
#pragma unroll
    for (int r = 0; r < 32; r += 8)
      dst[(size_t)(i0 + ty + r) * CDIM + c0 + tx] = f2b(t2[tx][ty + r]);
  } else {
    int i = (id - 16640) * 256 + threadIdx.x;
    if (i < ZERO_N) zbuf[i] = 0.0f;
  }
}

// ================= fused projection + context matrix (prefetch ladder) =========
// Per block: b, i-range 128 (heads ig*2, ig*2+1), n-chunk 512.
// Sequential K->V (spill-free: one GEMM acc live at a time). BK=32 double-
// buffered staging, STAGE(next) issued before compute, one barrier per step.
// (Verified 65.5 us config; T4 counted-vmcnt bolt-on REGRESSED 2x — regime gate:
// it requires the full 8-phase interleave, not this 2-phase ladder.)
__global__ __launch_bounds__(256, 2) void proj_ctx(
    const u16* __restrict__ Wkt, const u16* __restrict__ Wvt,
    const u16* __restrict__ ctx_bt, float* __restrict__ cm, float* __restrict__ ksum) {
  // 512 blocks = 4(ig) x 32(nc) x 4(b); chunked XCD swizzle
  int id = blockIdx.x;
  int swz = (id & 7) * 64 + (id >> 3);
  int ig = swz & 3, nc = (swz >> 2) & 31, b = swz >> 7;
  int i0 = ig * 128;
  const u16* Bt = ctx_bt + (size_t)b * NTOK * CDIM;

  __shared__ __align__(16) u16 smem[32768];   // 64 KiB -> 2 blocks/CU
  // staging buf p (p=0,1): A at p*8192, B at p*8192+4096 (each 128 rows x 32 k)
  u16* Ek = smem + 16384;    // [32K,64K) expK tile, dedicated
  u16* Vt = smem;            // [0,32K)   V tile, aliases both staging bufs

  int tid = threadIdx.x, wave = tid >> 6, lane = tid & 63;
  int wm = (wave >> 1) * 64, wn = (wave & 1) * 64;
  int quad = lane >> 4, l16 = lane & 15;
  int sr = lane >> 2, sc = (lane & 3) * 8;      // staging: 16 rows x 32 cols/chunk

  int hl = wave >> 1, dblk = (wave & 1) * 32;   // phase-2: wave -> (head, d-half)

  u16x8 ov;
#pragma unroll
  for (int t = 0; t < 8; t++) ov[t] = 0x3f80;   // bf16 1.0
  const bf16x8 ones = __builtin_bit_cast(bf16x8, ov);

  f32x4 acc_cm[2][4];
  f32x4 accS[2];
#pragma unroll
  for (int i = 0; i < 2; i++) {
    accS[i] = (f32x4)(0.0f);
#pragma unroll
    for (int j = 0; j < 4; j++) acc_cm[i][j] = (f32x4)(0.0f);
  }

  // stage step (kv, k-slice ks) into buf p. 16 chunks of 16rows x 32cols; 4/wave.
  auto stage = [&](int p, int kv, int ks, int n0) {
    int k0 = ks * 32;
    const u16* Asrc = kv ? Wvt : Wkt;
#pragma unroll
    for (int j = 0; j < 4; j++) {
      int c = wave * 4 + j;            // 0..15
      if (c < 8) {
        int row = c * 16 + sr;
        async_ld16(&Asrc[(size_t)(i0 + row) * CDIM + k0 + sc], &smem[p * 8192 + c * 512]);
      } else {
        int cb = c - 8, row = cb * 16 + sr;
        async_ld16(&Bt[(size_t)(n0 + row) * CDIM + k0 + sc], &smem[p * 8192 + 4096 + cb * 512]);
      }
    }
  };

  for (int nt = 0; nt < 4; nt++) {
    int n0 = nc * 512 + nt * 128;
    __syncthreads();                   // phase-2 reads of Vt/Ek done (or block start)
    stage(0, 0, 0, n0);
    __syncthreads();                   // buf0 ready (implicit vmcnt(0) drain)

    f32x4 acc[4][4];
#pragma unroll
    for (int i = 0; i < 4; i++)
#pragma unroll
      for (int j = 0; j < 4; j++) acc[i][j] = (f32x4)(0.0f);

#pragma unroll 2
    for (int s = 0; s < 16; s++) {     // s>>3 = kv, s&7 = k-slice
      int p = s & 1;
      if (s < 15) { int s1 = s + 1; stage(p ^ 1, s1 >> 3, s1 & 7, n0); }
      const u16* As = &smem[p * 8192];
      const u16* Bs = &smem[p * 8192 + 4096];
      bf16x8 af[4], bfr[4];
#pragma unroll
      for (int m = 0; m < 4; m++)
        af[m] = __builtin_bit_cast(bf16x8, *(const u16x8*)&As[(wm + m * 16 + l16) * 32 + quad * 8]);
#pragma unroll
      for (int e = 0; e < 4; e++)
        bfr[e] = __builtin_bit_cast(bf16x8, *(const u16x8*)&Bs[(wn + e * 16 + l16) * 32 + quad * 8]);
      // swapped operands: lane holds 4 consecutive n per frag
#pragma unroll
      for (int e = 0; e < 4; e++)
#pragma unroll
        for (int m = 0; m < 4; m++)
          acc[e][m] = __builtin_amdgcn_mfma_f32_16x16x32_bf16(bfr[e], af[m], acc[e][m], 0, 0, 0);

      if (s == 7) {
        // K-GEMM complete: write exp(K) to dedicated Ek (XOR-swz), reset acc for V
#pragma unroll
        for (int e = 0; e < 4; e++) {
          int nl0 = wn + e * 16 + quad * 4;
#pragma unroll
          for (int m = 0; m < 4; m++) {
            int row = wm + m * 16 + l16;
            u16x4 ok;
#pragma unroll
            for (int r = 0; r < 4; r++) ok[r] = f2b(__expf(acc[e][m][r]));
            unsigned byt = (unsigned)(row * 256 + nl0 * 2) ^ ((unsigned)(row & 7) << 4);
            *(u16x4*)((char*)Ek + byt) = ok;
            acc[e][m] = (f32x4)(0.0f);
          }
        }
      }
      __syncthreads();                 // next buf ready + buf-reuse safe
    }
    // acc holds V tile; staging fully drained & read -> Vt may alias it
#pragma unroll
    for (int e = 0; e < 4; e++) {
      int nl0 = wn + e * 16 + quad * 4;
#pragma unroll
      for (int m = 0; m < 4; m++) {
        int row = wm + m * 16 + l16;
        u16x4 ovv;
#pragma unroll
        for (int r = 0; r < 4; r++) ovv[r] = f2b(acc[e][m][r]);
        unsigned byt = (unsigned)(row * 256 + nl0 * 2) ^ ((unsigned)(row & 7) << 4);
        *(u16x4*)((char*)Vt + byt) = ovv;
      }
    }
    __syncthreads();                   // Ek/Vt visible to all waves
    // phase 2: per wave (hl, dblk): acc_cm[m2][e2] += Ek_row · Vt_row over 128 n
#pragma unroll
    for (int kk = 0; kk < 128; kk += 32) {
      int ko = kk + quad * 8;
      bf16x8 ea[2], vb[4];
#pragma unroll
      for (int m2 = 0; m2 < 2; m2++) {
        int row = hl * 64 + dblk + m2 * 16 + l16;
        unsigned byt = (unsigned)(row * 256 + ko * 2) ^ ((unsigned)(row & 7) << 4);
        ea[m2] = __builtin_bit_cast(bf16x8, *(const u16x8*)((char*)Ek + byt));
      }
#pragma unroll
      for (int e2 = 0; e2 < 4; e2++) {
        int row = hl * 64 + e2 * 16 + l16;
        unsigned byt = (unsigned)(row * 256 + ko * 2) ^ ((unsigned)(row & 7) << 4);
        vb[e2] = __builtin_bit_cast(bf16x8, *(const u16x8*)((char*)Vt + byt));
      }
#pragma unroll
      for (int m2 = 0; m2 < 2; m2++) {
        accS[m2] = __builtin_amdgcn_mfma_f32_16x16x32_bf16(ea[m2], ones, accS[m2], 0, 0, 0);
#pragma unroll
        for (int e2 = 0; e2 < 4; e2++)
          acc_cm[m2][e2] = __builtin_amdgcn_mfma_f32_16x16x32_bf16(ea[m2], vb[e2], acc_cm[m2][e2], 0, 0, 0);
      }
    }
    // next nt's first __syncthreads protects Ek/Vt vs staging overwrite
  }
  // epilogue: waves own disjoint (h, d-half) -> no intra-block contention
  int h = ig * 2 + hl;
  float* cmp = cm + (size_t)(b * 8 + h) * 64 * 64;
#pragma unroll
  for (int m2 = 0; m2 < 2; m2++)
#pragma unroll
    for (int e2 = 0; e2 < 4; e2++)
#pragma unroll
      for (int r = 0; r < 4; r++) {
        int d = dblk + m2 * 16 + quad * 4 + r;
        int e = e2 * 16 + l16;
        atomicAdd(&cmp[d * 64 + e], acc_cm[m2][e2][r]);
      }
  if (l16 == 0) {
#pragma unroll
    for (int m2 = 0; m2 < 2; m2++)
#pragma unroll
      for (int r = 0; r < 4; r++) {
        int d = dblk + m2 * 16 + quad * 4 + r;
        atomicAdd(&ksum[(size_t)b * INNERD + h * 64 + d], accS[m2][r]);
      }
  }
}

// ---------------- weff[b][i=h*64+d][c] = (sum_e cm[d][e]*Wo[h*64+e][c])/ksum ---
__global__ __launch_bounds__(256) void weff_k(
    const float* __restrict__ cm, const float* __restrict__ Wo,
    const float* __restrict__ ksum, float* __restrict__ weff) {
  int bi = blockIdx.x;            // 0..2047
  int b = bi >> 9, i = bi & 511, h = i >> 6, d = i & 63;
  const float* cmr = cm + ((size_t)(b * 8 + h) * 64 + d) * 64;
  __shared__ float cs[64];
  if (threadIdx.x < 64) cs[threadIdx.x] = cmr[threadIdx.x];
  __syncthreads();
  float inv = 1.0f / ksum[(size_t)b * INNERD + i];
  int c = threadIdx.x;
  float s = 0.0f;
#pragma unroll 8
  for (int e = 0; e < 64; e++) s += cs[e] * Wo[(size_t)(h * 64 + e) * CDIM + c];
  weff[(size_t)bi * CDIM + c] = s * inv;
}

// ---------------- Gt[b][c][c'] = sum_i weff[b][i][c] * Wq[c'][i]  (bf16 out) ---
// Wq (DIM=256, INNER=512) row-major: Wq[cp][i] is CONSECUTIVE in i -> f32x4
// streams (16B/lane, 4x cacheline reuse) and full-f32 weights (less rounding
// than the old bf16 Wq_t copy).
__global__ __launch_bounds__(256) void gt_k(
    const float* __restrict__ weff, const float* __restrict__ Wq, u16* __restrict__ Gt) {
  int bc = blockIdx.x;            // 0..1023
  int b = bc >> 8, c = bc & 255;
  __shared__ float ws[512];
  for (int j = threadIdx.x; j < 512; j += 256)
    ws[j] = weff[((size_t)b * 512 + j) * CDIM + c];
  __syncthreads();
  int cp = threadIdx.x;
  float s = 0.0f;
#pragma unroll 8
  for (int i = 0; i < 512; i += 4) {
    f32x4 q = *(const f32x4*)&Wq[(size_t)cp * INNERD + i];
    s += ws[i] * q[0] + ws[i + 1] * q[1] + ws[i + 2] * q[2] + ws[i + 3] * q[3];
  }
  Gt[(size_t)bc * CDIM + cp] = f2b(s);
}

// ---------------- final: out[b][c][n] = x + bo[c] + sum_c' Gt[c][c'] x_bt[n][c']
// Prefetch ladder (BK=32, 8 steps); f32x4 residual epilogue.
__global__ __launch_bounds__(256) void final_gemm(
    const u16* __restrict__ Gt, const u16* __restrict__ x_bt,
    const float* __restrict__ x, const float* __restrict__ bo,
    float* __restrict__ out) {
  // flattened grid 1024 = 2(x) * 128(y) * 4(z); chunked XCD swizzle
  int id = blockIdx.x;
  int swz = (id & 7) * 128 + (id >> 3);
  int bx = swz & 1, by = (swz >> 1) & 127, b = swz >> 8;
  const u16* A  = Gt + (size_t)b * CDIM * CDIM;
  const u16* Bt = x_bt + (size_t)b * NTOK * CDIM;
  const float* xb = x + (size_t)b * CDIM * NTOK;
  float* ob = out + (size_t)b * CDIM * NTOK;
  int i0 = bx * 128;
  int n0 = by * 128;

  __shared__ __align__(16) u16 smem2[16384];   // 32 KiB: 2 bufs x (A 4K + B 4K u16)

  int tid = threadIdx.x;
  int wave = tid >> 6, lane = tid & 63;
  int wm = (wave >> 1) * 64, wn = (wave & 1) * 64;
  int quad = lane >> 4, l16 = lane & 15;
  int sr = lane >> 2, sc = (lane & 3) * 8;

  auto stage = [&](int p, int ks) {
    int k0 = ks * 32;
#pragma unroll
    for (int j = 0; j < 4; j++) {
      int c = wave * 4 + j;
      if (c < 8) {
        int row = c * 16 + sr;
        async_ld16(&A[(size_t)(i0 + row) * CDIM + k0 + sc], &smem2[p * 8192 + c * 512]);
      } else {
        int cb = c - 8, row = cb * 16 + sr;
        async_ld16(&Bt[(size_t)(n0 + row) * CDIM + k0 + sc], &smem2[p * 8192 + 4096 + cb * 512]);
      }
    }
  };

  f32x4 acc[4][4];   // [e:n-frag][m:c-frag]
#pragma unroll
  for (int i = 0; i < 4; i++)
#pragma unroll
    for (int j = 0; j < 4; j++) acc[i][j] = (f32x4)(0.0f);

  stage(0, 0);
  __syncthreads();
#pragma unroll 2
  for (int s = 0; s < 8; s++) {
    int p = s & 1;
    if (s < 7) stage(p ^ 1, s + 1);
    const u16* As = &smem2[p * 8192];
    const u16* Bs = &smem2[p * 8192 + 4096];
    bf16x8 af[4], bfr[4];
#pragma unroll
    for (int m = 0; m < 4; m++)
      af[m] = __builtin_bit_cast(bf16x8, *(const u16x8*)&As[(wm + m * 16 + l16) * 32 + quad * 8]);
#pragma unroll
    for (int e = 0; e < 4; e++)
      bfr[e] = __builtin_bit_cast(bf16x8, *(const u16x8*)&Bs[(wn + e * 16 + l16) * 32 + quad * 8]);
#pragma unroll
    for (int e = 0; e < 4; e++)
#pragma unroll
      for (int m = 0; m < 4; m++)
        acc[e][m] = __builtin_amdgcn_mfma_f32_16x16x32_bf16(bfr[e], af[m], acc[e][m], 0, 0, 0);
    if (s < 7) __syncthreads();
  }
  // lane's acc[e][m][r]: c = i0+wm+m*16+l16, n = n0+wn+e*16+quad*4+r
#pragma unroll
  for (int e = 0; e < 4; e++) {
    int nb = n0 + wn + e * 16 + quad * 4;
#pragma unroll
    for (int m = 0; m < 4; m++) {
      int c = i0 + wm + m * 16 + l16;
      f32x4 xv = *(const f32x4*)&xb[(size_t)c * NTOK + nb];
      f32x4 r;
      float bc = bo[c];
#pragma unroll
      for (int t = 0; t < 4; t++) r[t] = acc[e][m][t] + xv[t] + bc;
      *(f32x4*)&ob[(size_t)c * NTOK + nb] = r;
    }
  }
}

extern "C" void kernel_launch(void* const* d_in, const int* in_sizes, int n_in,
                              void* d_out, int out_size, void* d_ws, size_t ws_size,
                              hipStream_t stream) {
  const float* x   = (const float*)d_in[0];
  const float* ctx = (const float*)d_in[1];
  const float* Wq  = (const float*)d_in[2];
  const float* Wk  = (const float*)d_in[3];
  const float* Wv  = (const float*)d_in[4];
  const float* Wo  = (const float*)d_in[5];
  const float* bo  = (const float*)d_in[6];
  float* out = (float*)d_out;

  char* ws = (char*)d_ws;
  u16* ctx_bt = (u16*)ws;  ws += (size_t)BATCH * NTOK * CDIM * 2;     // 32 MiB
  u16* x_bt   = (u16*)ws;  ws += (size_t)BATCH * NTOK * CDIM * 2;     // 32 MiB
  u16* Wk_t   = (u16*)ws;  ws += (size_t)INNERD * CDIM * 2;
  u16* Wv_t   = (u16*)ws;  ws += (size_t)INNERD * CDIM * 2;
  float* cm   = (float*)ws; ws += (size_t)BATCH * 8 * 64 * 64 * 4;    // 512 KiB
  float* ksum = (float*)ws; ws += (size_t)BATCH * INNERD * 4;         // 8 KiB (contiguous after cm)
  float* weff = (float*)ws; ws += (size_t)BATCH * INNERD * CDIM * 4;  // 2 MiB
  u16* Gt     = (u16*)ws;  ws += (size_t)BATCH * CDIM * CDIM * 2;

  prep<<<dim3(17160), 256, 0, stream>>>(x, ctx, Wk, Wv, x_bt, ctx_bt,
                                        Wk_t, Wv_t, cm /* zero cm+ksum */);
  proj_ctx<<<dim3(512), 256, 0, stream>>>(Wk_t, Wv_t, ctx_bt, cm, ksum);
  weff_k<<<BATCH * INNERD, 256, 0, stream>>>(cm, Wo, ksum, weff);
  gt_k<<<BATCH * CDIM, 256, 0, stream>>>(weff, Wq, Gt);
  final_gemm<<<dim3(1024), 256, 0, stream>>>(Gt, x_bt, x, bo, out);
}

// Round 10
// 297.598 us; speedup vs baseline: 1.2839x; 1.1509x over previous
//
#include <hip/hip_runtime.h>

typedef unsigned short u16;
typedef u16   u16x4  __attribute__((ext_vector_type(4)));
typedef u16   u16x8  __attribute__((ext_vector_type(8)));
typedef __bf16 bf16x8 __attribute__((ext_vector_type(8)));
typedef float f32x4  __attribute__((ext_vector_type(4)));

constexpr int BATCH  = 4;
constexpr int CDIM   = 256;
constexpr int NTOK   = 16384;   // 128*128
constexpr int INNERD = 512;

// native bf16 converts (v_cvt_pk_bf16_f32, RNE)
__device__ __forceinline__ u16 f2b(float f) {
  return __builtin_bit_cast(u16, (__bf16)f);
}
__device__ __forceinline__ float b2f(u16 b) {
  return (float)__builtin_bit_cast(__bf16, b);
}

// async global->LDS, 16B per lane. LDS dest must be WAVE-UNIFORM base;
// HW writes lane i's data at base + i*16. Global src is per-lane.
__device__ __forceinline__ void async_ld16(const u16* g, u16* l) {
  __builtin_amdgcn_global_load_lds(
      (const __attribute__((address_space(1))) void*)g,
      (__attribute__((address_space(3))) void*)l, 16, 0, 0);
}

// ---------------- prep: transpose_cvt + wtrans(K,V) + Wq cvt + zero fused ------
// id [0,16384): transpose (b,c,n) f32 -> (b,n,c) bf16 for x and ctx
// id [16384,16640): weight transpose (256,512) f32 -> (512,256) bf16 for Wk,Wv
// id [16640,16704): Wq (256,512) f32 -> bf16 copy (NO transpose; row-major in i)
// id [16704,17224): zero cm/ksum scratch
constexpr int ZERO_N = BATCH * 8 * 64 * 64 + BATCH * INNERD;  // 133120
__global__ __launch_bounds__(256) void prep(
    const float* __restrict__ x, const float* __restrict__ ctx,
    const float* __restrict__ Wk, const float* __restrict__ Wv,
    const float* __restrict__ Wq,
    u16* __restrict__ xt, u16* __restrict__ ct,
    u16* __restrict__ kt, u16* __restrict__ vt, u16* __restrict__ qc,
    float* __restrict__ zbuf) {
  __shared__ float tile[64][33];   // reused by both transpose branches
  int id = blockIdx.x;
  if (id < 16384) {
    int bx = id & 511, by = (id >> 9) & 3, zb = id >> 11;
    int b = zb >> 1;
    const float* src = (zb & 1) ? ctx : x;
    u16* dst = (zb & 1) ? ct : xt;
    src += (size_t)b * CDIM * NTOK;
    dst += (size_t)b * NTOK * CDIM;
    int n0 = bx * 32, c0 = by * 64;
    int tx = threadIdx.x & 31, ty = threadIdx.x >> 5;   // ty 0..7
#pragma unroll
    for (int i = 0; i < 64; i += 8)
      tile[ty + i][tx] = src[(size_t)(c0 + ty + i) * NTOK + n0 + tx];
    __syncthreads();
    int nl = threadIdx.x >> 3;          // 0..31
    int cl = (threadIdx.x & 7) * 8;     // 0..56
    u16x8 o;
#pragma unroll
    for (int j = 0; j < 8; j++) o[j] = f2b(tile[cl + j][nl]);
    *(u16x8*)&dst[(size_t)(n0 + nl) * CDIM + c0 + cl] = o;
  } else if (id < 16640) {
    int idw = id - 16384;
    int bx = idw & 15, by = (idw >> 4) & 7, bz = idw >> 7;  // 16 x 8 x 2
    float (*t2)[33] = (float(*)[33])tile;
    const float* src = bz == 0 ? Wk : Wv;
    u16* dst = bz == 0 ? kt : vt;
    int i0 = bx * 32, c0 = by * 32;
    int tx = threadIdx.x & 31, ty = threadIdx.x >> 5;
#pragma unroll
    for (int r = 0; r < 32; r += 8)
      t2[ty + r][tx] = src[(size_t)(c0 + ty + r) * INNERD + i0 + tx];
    __syncthreads();
#pragma unroll
    for (int r = 0; r < 32; r += 8)
      dst[(size_t)(i0 + ty + r) * CDIM + c0 + tx] = f2b(t2[tx][ty + r]);
  } else if (id < 16704) {
    // straight f32->bf16 copy of Wq: 131072 elems, 64 blocks x 256 thr x 8
    size_t off = (size_t)(id - 16640) * 2048 + threadIdx.x * 8;
    f32x4 a = *(const f32x4*)&Wq[off];
    f32x4 c = *(const f32x4*)&Wq[off + 4];
    u16x8 o;
#pragma unroll
    for (int j = 0; j < 4; j++) { o[j] = f2b(a[j]); o[j + 4] = f2b(c[j]); }
    *(u16x8*)&qc[off] = o;
  } else {
    int i = (id - 16704) * 256 + threadIdx.x;
    if (i < ZERO_N) zbuf[i] = 0.0f;
  }
}

// ================= fused projection + context matrix (prefetch ladder) =========
// Per block: b, i-range 128 (heads ig*2, ig*2+1), n-chunk 512.
// Sequential K->V (spill-free). BK=32 double-buffered staging, STAGE(next)
// before compute, one barrier per step. Verified 65 us config — do not touch.
__global__ __launch_bounds__(256, 2) void proj_ctx(
    const u16* __restrict__ Wkt, const u16* __restrict__ Wvt,
    const u16* __restrict__ ctx_bt, float* __restrict__ cm, float* __restrict__ ksum) {
  // 512 blocks = 4(ig) x 32(nc) x 4(b); chunked XCD swizzle
  int id = blockIdx.x;
  int swz = (id & 7) * 64 + (id >> 3);
  int ig = swz & 3, nc = (swz >> 2) & 31, b = swz >> 7;
  int i0 = ig * 128;
  const u16* Bt = ctx_bt + (size_t)b * NTOK * CDIM;

  __shared__ __align__(16) u16 smem[32768];   // 64 KiB -> 2 blocks/CU
  // staging buf p (p=0,1): A at p*8192, B at p*8192+4096 (each 128 rows x 32 k)
  u16* Ek = smem + 16384;    // [32K,64K) expK tile, dedicated
  u16* Vt = smem;            // [0,32K)   V tile, aliases both staging bufs

  int tid = threadIdx.x, wave = tid >> 6, lane = tid & 63;
  int wm = (wave >> 1) * 64, wn = (wave & 1) * 64;
  int quad = lane >> 4, l16 = lane & 15;
  int sr = lane >> 2, sc = (lane & 3) * 8;      // staging: 16 rows x 32 cols/chunk

  int hl = wave >> 1, dblk = (wave & 1) * 32;   // phase-2: wave -> (head, d-half)

  u16x8 ov;
#pragma unroll
  for (int t = 0; t < 8; t++) ov[t] = 0x3f80;   // bf16 1.0
  const bf16x8 ones = __builtin_bit_cast(bf16x8, ov);

  f32x4 acc_cm[2][4];
  f32x4 accS[2];
#pragma unroll
  for (int i = 0; i < 2; i++) {
    accS[i] = (f32x4)(0.0f);
#pragma unroll
    for (int j = 0; j < 4; j++) acc_cm[i][j] = (f32x4)(0.0f);
  }

  // stage step (kv, k-slice ks) into buf p. 16 chunks of 16rows x 32cols; 4/wave.
  auto stage = [&](int p, int kv, int ks, int n0) {
    int k0 = ks * 32;
    const u16* Asrc = kv ? Wvt : Wkt;
#pragma unroll
    for (int j = 0; j < 4; j++) {
      int c = wave * 4 + j;            // 0..15
      if (c < 8) {
        int row = c * 16 + sr;
        async_ld16(&Asrc[(size_t)(i0 + row) * CDIM + k0 + sc], &smem[p * 8192 + c * 512]);
      } else {
        int cb = c - 8, row = cb * 16 + sr;
        async_ld16(&Bt[(size_t)(n0 + row) * CDIM + k0 + sc], &smem[p * 8192 + 4096 + cb * 512]);
      }
    }
  };

  for (int nt = 0; nt < 4; nt++) {
    int n0 = nc * 512 + nt * 128;
    __syncthreads();                   // phase-2 reads of Vt/Ek done (or block start)
    stage(0, 0, 0, n0);
    __syncthreads();                   // buf0 ready (implicit vmcnt(0) drain)

    f32x4 acc[4][4];
#pragma unroll
    for (int i = 0; i < 4; i++)
#pragma unroll
      for (int j = 0; j < 4; j++) acc[i][j] = (f32x4)(0.0f);

#pragma unroll 2
    for (int s = 0; s < 16; s++) {     // s>>3 = kv, s&7 = k-slice
      int p = s & 1;
      if (s < 15) { int s1 = s + 1; stage(p ^ 1, s1 >> 3, s1 & 7, n0); }
      const u16* As = &smem[p * 8192];
      const u16* Bs = &smem[p * 8192 + 4096];
      bf16x8 af[4], bfr[4];
#pragma unroll
      for (int m = 0; m < 4; m++)
        af[m] = __builtin_bit_cast(bf16x8, *(const u16x8*)&As[(wm + m * 16 + l16) * 32 + quad * 8]);
#pragma unroll
      for (int e = 0; e < 4; e++)
        bfr[e] = __builtin_bit_cast(bf16x8, *(const u16x8*)&Bs[(wn + e * 16 + l16) * 32 + quad * 8]);
      // swapped operands: lane holds 4 consecutive n per frag
#pragma unroll
      for (int e = 0; e < 4; e++)
#pragma unroll
        for (int m = 0; m < 4; m++)
          acc[e][m] = __builtin_amdgcn_mfma_f32_16x16x32_bf16(bfr[e], af[m], acc[e][m], 0, 0, 0);

      if (s == 7) {
        // K-GEMM complete: write exp(K) to dedicated Ek (XOR-swz), reset acc for V
#pragma unroll
        for (int e = 0; e < 4; e++) {
          int nl0 = wn + e * 16 + quad * 4;
#pragma unroll
          for (int m = 0; m < 4; m++) {
            int row = wm + m * 16 + l16;
            u16x4 ok;
#pragma unroll
            for (int r = 0; r < 4; r++) ok[r] = f2b(__expf(acc[e][m][r]));
            unsigned byt = (unsigned)(row * 256 + nl0 * 2) ^ ((unsigned)(row & 7) << 4);
            *(u16x4*)((char*)Ek + byt) = ok;
            acc[e][m] = (f32x4)(0.0f);
          }
        }
      }
      __syncthreads();                 // next buf ready + buf-reuse safe
    }
    // acc holds V tile; staging fully drained & read -> Vt may alias it
#pragma unroll
    for (int e = 0; e < 4; e++) {
      int nl0 = wn + e * 16 + quad * 4;
#pragma unroll
      for (int m = 0; m < 4; m++) {
        int row = wm + m * 16 + l16;
        u16x4 ovv;
#pragma unroll
        for (int r = 0; r < 4; r++) ovv[r] = f2b(acc[e][m][r]);
        unsigned byt = (unsigned)(row * 256 + nl0 * 2) ^ ((unsigned)(row & 7) << 4);
        *(u16x4*)((char*)Vt + byt) = ovv;
      }
    }
    __syncthreads();                   // Ek/Vt visible to all waves
    // phase 2: per wave (hl, dblk): acc_cm[m2][e2] += Ek_row · Vt_row over 128 n
#pragma unroll
    for (int kk = 0; kk < 128; kk += 32) {
      int ko = kk + quad * 8;
      bf16x8 ea[2], vb[4];
#pragma unroll
      for (int m2 = 0; m2 < 2; m2++) {
        int row = hl * 64 + dblk + m2 * 16 + l16;
        unsigned byt = (unsigned)(row * 256 + ko * 2) ^ ((unsigned)(row & 7) << 4);
        ea[m2] = __builtin_bit_cast(bf16x8, *(const u16x8*)((char*)Ek + byt));
      }
#pragma unroll
      for (int e2 = 0; e2 < 4; e2++) {
        int row = hl * 64 + e2 * 16 + l16;
        unsigned byt = (unsigned)(row * 256 + ko * 2) ^ ((unsigned)(row & 7) << 4);
        vb[e2] = __builtin_bit_cast(bf16x8, *(const u16x8*)((char*)Vt + byt));
      }
#pragma unroll
      for (int m2 = 0; m2 < 2; m2++) {
        accS[m2] = __builtin_amdgcn_mfma_f32_16x16x32_bf16(ea[m2], ones, accS[m2], 0, 0, 0);
#pragma unroll
        for (int e2 = 0; e2 < 4; e2++)
          acc_cm[m2][e2] = __builtin_amdgcn_mfma_f32_16x16x32_bf16(ea[m2], vb[e2], acc_cm[m2][e2], 0, 0, 0);
      }
    }
    // next nt's first __syncthreads protects Ek/Vt vs staging overwrite
  }
  // epilogue: waves own disjoint (h, d-half) -> no intra-block contention
  int h = ig * 2 + hl;
  float* cmp = cm + (size_t)(b * 8 + h) * 64 * 64;
#pragma unroll
  for (int m2 = 0; m2 < 2; m2++)
#pragma unroll
    for (int e2 = 0; e2 < 4; e2++)
#pragma unroll
      for (int r = 0; r < 4; r++) {
        int d = dblk + m2 * 16 + quad * 4 + r;
        int e = e2 * 16 + l16;
        atomicAdd(&cmp[d * 64 + e], acc_cm[m2][e2][r]);
      }
  if (l16 == 0) {
#pragma unroll
    for (int m2 = 0; m2 < 2; m2++)
#pragma unroll
      for (int r = 0; r < 4; r++) {
        int d = dblk + m2 * 16 + quad * 4 + r;
        atomicAdd(&ksum[(size_t)b * INNERD + h * 64 + d], accS[m2][r]);
      }
  }
}

// ---------------- weff_t[b][c][i] = (sum_e cm[d][e]*Wo[h*64+e][c])/ksum (bf16) -
// TRANSPOSED + bf16 output so gt_k can stage it row-major-in-i via async_ld16.
// The u16 scatter stores (stride 1KB across lanes) are fire-and-forget; 1 MB total.
__global__ __launch_bounds__(256) void weff_k(
    const float* __restrict__ cm, const float* __restrict__ Wo,
    const float* __restrict__ ksum, u16* __restrict__ weff_t) {
  int bi = blockIdx.x;            // 0..2047
  int b = bi >> 9, i = bi & 511, h = i >> 6, d = i & 63;
  const float* cmr = cm + ((size_t)(b * 8 + h) * 64 + d) * 64;
  __shared__ float cs[64];
  if (threadIdx.x < 64) cs[threadIdx.x] = cmr[threadIdx.x];
  __syncthreads();
  float inv = 1.0f / ksum[(size_t)b * INNERD + i];
  int c = threadIdx.x;
  float s = 0.0f;
#pragma unroll 8
  for (int e = 0; e < 64; e++) s += cs[e] * Wo[(size_t)(h * 64 + e) * CDIM + c];
  weff_t[((size_t)b * CDIM + c) * INNERD + i] = f2b(s * inv);
}

// ---------------- Gt[b][c][c'] = sum_i weff_t[b][c][i] * Wqc[c'][i]  (MFMA) ----
// Both operands row-major in the contraction axis i -> clean final_gemm-style
// ladder. 16 blocks (2x2x4b), 128^2 tile, K=512, BK=32 double-buffered.
__global__ __launch_bounds__(256) void gt_k(
    const u16* __restrict__ weff_t, const u16* __restrict__ Wqc, u16* __restrict__ Gt) {
  int id = blockIdx.x;            // 16 = 2(x) * 2(y) * 4(b)
  int bx = id & 1, by = (id >> 1) & 1, b = id >> 2;
  const u16* A  = weff_t + (size_t)b * CDIM * INNERD;   // [c][512]
  const u16* Bt = Wqc;                                  // [c'][512]
  int i0 = bx * 128;              // c rows
  int n0 = by * 128;              // c' cols

  __shared__ __align__(16) u16 smem3[16384];   // 2 bufs x (A 4K + B 4K u16)

  int tid = threadIdx.x;
  int wave = tid >> 6, lane = tid & 63;
  int wm = (wave >> 1) * 64, wn = (wave & 1) * 64;
  int quad = lane >> 4, l16 = lane & 15;
  int sr = lane >> 2, sc = (lane & 3) * 8;

  auto stage = [&](int p, int ks) {
    int k0 = ks * 32;
#pragma unroll
    for (int j = 0; j < 4; j++) {
      int c = wave * 4 + j;
      if (c < 8) {
        int row = c * 16 + sr;
        async_ld16(&A[(size_t)(i0 + row) * INNERD + k0 + sc], &smem3[p * 8192 + c * 512]);
      } else {
        int cb = c - 8, row = cb * 16 + sr;
        async_ld16(&Bt[(size_t)(n0 + row) * INNERD + k0 + sc], &smem3[p * 8192 + 4096 + cb * 512]);
      }
    }
  };

  f32x4 acc[4][4];   // [e:c'-frag][m:c-frag]
#pragma unroll
  for (int i = 0; i < 4; i++)
#pragma unroll
    for (int j = 0; j < 4; j++) acc[i][j] = (f32x4)(0.0f);

  stage(0, 0);
  __syncthreads();
#pragma unroll 2
  for (int s = 0; s < 16; s++) {       // K=512 -> 16 BK=32 steps
    int p = s & 1;
    if (s < 15) stage(p ^ 1, s + 1);
    const u16* As = &smem3[p * 8192];
    const u16* Bs = &smem3[p * 8192 + 4096];
    bf16x8 af[4], bfr[4];
#pragma unroll
    for (int m = 0; m < 4; m++)
      af[m] = __builtin_bit_cast(bf16x8, *(const u16x8*)&As[(wm + m * 16 + l16) * 32 + quad * 8]);
#pragma unroll
    for (int e = 0; e < 4; e++)
      bfr[e] = __builtin_bit_cast(bf16x8, *(const u16x8*)&Bs[(wn + e * 16 + l16) * 32 + quad * 8]);
#pragma unroll
    for (int e = 0; e < 4; e++)
#pragma unroll
      for (int m = 0; m < 4; m++)
        acc[e][m] = __builtin_amdgcn_mfma_f32_16x16x32_bf16(bfr[e], af[m], acc[e][m], 0, 0, 0);
    if (s < 15) __syncthreads();
  }
  // lane's acc[e][m][r]: c = i0+wm+m*16+l16, c' = n0+wn+e*16+quad*4+r
#pragma unroll
  for (int e = 0; e < 4; e++) {
    int nb = n0 + wn + e * 16 + quad * 4;
#pragma unroll
    for (int m = 0; m < 4; m++) {
      int c = i0 + wm + m * 16 + l16;
      u16x4 o;
#pragma unroll
      for (int r = 0; r < 4; r++) o[r] = f2b(acc[e][m][r]);
      *(u16x4*)&Gt[((size_t)b * CDIM + c) * CDIM + nb] = o;
    }
  }
}

// ---------------- final: out[b][c][n] = x + bo[c] + sum_c' Gt[c][c'] x_bt[n][c']
// Prefetch ladder (BK=32, 8 steps); f32x4 residual epilogue.
__global__ __launch_bounds__(256) void final_gemm(
    const u16* __restrict__ Gt, const u16* __restrict__ x_bt,
    const float* __restrict__ x, const float* __restrict__ bo,
    float* __restrict__ out) {
  // flattened grid 1024 = 2(x) * 128(y) * 4(z); chunked XCD swizzle
  int id = blockIdx.x;
  int swz = (id & 7) * 128 + (id >> 3);
  int bx = swz & 1, by = (swz >> 1) & 127, b = swz >> 8;
  const u16* A  = Gt + (size_t)b * CDIM * CDIM;
  const u16* Bt = x_bt + (size_t)b * NTOK * CDIM;
  const float* xb = x + (size_t)b * CDIM * NTOK;
  float* ob = out + (size_t)b * CDIM * NTOK;
  int i0 = bx * 128;
  int n0 = by * 128;

  __shared__ __align__(16) u16 smem2[16384];   // 32 KiB: 2 bufs x (A 4K + B 4K u16)

  int tid = threadIdx.x;
  int wave = tid >> 6, lane = tid & 63;
  int wm = (wave >> 1) * 64, wn = (wave & 1) * 64;
  int quad = lane >> 4, l16 = lane & 15;
  int sr = lane >> 2, sc = (lane & 3) * 8;

  auto stage = [&](int p, int ks) {
    int k0 = ks * 32;
#pragma unroll
    for (int j = 0; j < 4; j++) {
      int c = wave * 4 + j;
      if (c < 8) {
        int row = c * 16 + sr;
        async_ld16(&A[(size_t)(i0 + row) * CDIM + k0 + sc], &smem2[p * 8192 + c * 512]);
      } else {
        int cb = c - 8, row = cb * 16 + sr;
        async_ld16(&Bt[(size_t)(n0 + row) * CDIM + k0 + sc], &smem2[p * 8192 + 4096 + cb * 512]);
      }
    }
  };

  f32x4 acc[4][4];   // [e:n-frag][m:c-frag]
#pragma unroll
  for (int i = 0; i < 4; i++)
#pragma unroll
    for (int j = 0; j < 4; j++) acc[i][j] = (f32x4)(0.0f);

  stage(0, 0);
  __syncthreads();
#pragma unroll 2
  for (int s = 0; s < 8; s++) {
    int p = s & 1;
    if (s < 7) stage(p ^ 1, s + 1);
    const u16* As = &smem2[p * 8192];
    const u16* Bs = &smem2[p * 8192 + 4096];
    bf16x8 af[4], bfr[4];
#pragma unroll
    for (int m = 0; m < 4; m++)
      af[m] = __builtin_bit_cast(bf16x8, *(const u16x8*)&As[(wm + m * 16 + l16) * 32 + quad * 8]);
#pragma unroll
    for (int e = 0; e < 4; e++)
      bfr[e] = __builtin_bit_cast(bf16x8, *(const u16x8*)&Bs[(wn + e * 16 + l16) * 32 + quad * 8]);
#pragma unroll
    for (int e = 0; e < 4; e++)
#pragma unroll
      for (int m = 0; m < 4; m++)
        acc[e][m] = __builtin_amdgcn_mfma_f32_16x16x32_bf16(bfr[e], af[m], acc[e][m], 0, 0, 0);
    if (s < 7) __syncthreads();
  }
  // lane's acc[e][m][r]: c = i0+wm+m*16+l16, n = n0+wn+e*16+quad*4+r
#pragma unroll
  for (int e = 0; e < 4; e++) {
    int nb = n0 + wn + e * 16 + quad * 4;
#pragma unroll
    for (int m = 0; m < 4; m++) {
      int c = i0 + wm + m * 16 + l16;
      f32x4 xv = *(const f32x4*)&xb[(size_t)c * NTOK + nb];
      f32x4 r;
      float bc = bo[c];
#pragma unroll
      for (int t = 0; t < 4; t++) r[t] = acc[e][m][t] + xv[t] + bc;
      *(f32x4*)&ob[(size_t)c * NTOK + nb] = r;
    }
  }
}

extern "C" void kernel_launch(void* const* d_in, const int* in_sizes, int n_in,
                              void* d_out, int out_size, void* d_ws, size_t ws_size,
                              hipStream_t stream) {
  const float* x   = (const float*)d_in[0];
  const float* ctx = (const float*)d_in[1];
  const float* Wq  = (const float*)d_in[2];
  const float* Wk  = (const float*)d_in[3];
  const float* Wv  = (const float*)d_in[4];
  const float* Wo  = (const float*)d_in[5];
  const float* bo  = (const float*)d_in[6];
  float* out = (float*)d_out;

  char* ws = (char*)d_ws;
  u16* ctx_bt = (u16*)ws;  ws += (size_t)BATCH * NTOK * CDIM * 2;     // 32 MiB
  u16* x_bt   = (u16*)ws;  ws += (size_t)BATCH * NTOK * CDIM * 2;     // 32 MiB
  u16* Wk_t   = (u16*)ws;  ws += (size_t)INNERD * CDIM * 2;
  u16* Wv_t   = (u16*)ws;  ws += (size_t)INNERD * CDIM * 2;
  u16* Wqc    = (u16*)ws;  ws += (size_t)CDIM * INNERD * 2;           // 256 KiB
  float* cm   = (float*)ws; ws += (size_t)BATCH * 8 * 64 * 64 * 4;    // 512 KiB
  float* ksum = (float*)ws; ws += (size_t)BATCH * INNERD * 4;         // 8 KiB (contiguous after cm)
  u16* weff_t = (u16*)ws;  ws += (size_t)BATCH * CDIM * INNERD * 2;   // 1 MiB
  u16* Gt     = (u16*)ws;  ws += (size_t)BATCH * CDIM * CDIM * 2;

  prep<<<dim3(17224), 256, 0, stream>>>(x, ctx, Wk, Wv, Wq, x_bt, ctx_bt,
                                        Wk_t, Wv_t, Wqc, cm /* zero cm+ksum */);
  proj_ctx<<<dim3(512), 256, 0, stream>>>(Wk_t, Wv_t, ctx_bt, cm, ksum);
  weff_k<<<BATCH * INNERD, 256, 0, stream>>>(cm, Wo, ksum, weff_t);
  gt_k<<<dim3(16), 256, 0, stream>>>(weff_t, Wqc, Gt);
  final_gemm<<<dim3(1024), 256, 0, stream>>>(Gt, x_bt, x, bo, out);
}

// Round 11
// 295.080 us; speedup vs baseline: 1.2948x; 1.0085x over previous
//
#include <hip/hip_runtime.h>

typedef unsigned short u16;
typedef u16   u16x4  __attribute__((ext_vector_type(4)));
typedef u16   u16x8  __attribute__((ext_vector_type(8)));
typedef __bf16 bf16x8 __attribute__((ext_vector_type(8)));
typedef float f32x4  __attribute__((ext_vector_type(4)));

constexpr int BATCH  = 4;
constexpr int CDIM   = 256;
constexpr int NTOK   = 16384;   // 128*128
constexpr int INNERD = 512;

// native bf16 converts (v_cvt_pk_bf16_f32, RNE)
__device__ __forceinline__ u16 f2b(float f) {
  return __builtin_bit_cast(u16, (__bf16)f);
}
__device__ __forceinline__ float b2f(u16 b) {
  return (float)__builtin_bit_cast(__bf16, b);
}

// async global->LDS, 16B per lane. LDS dest must be WAVE-UNIFORM base;
// HW writes lane i's data at base + i*16. Global src is per-lane.
__device__ __forceinline__ void async_ld16(const u16* g, u16* l) {
  __builtin_amdgcn_global_load_lds(
      (const __attribute__((address_space(1))) void*)g,
      (__attribute__((address_space(3))) void*)l, 16, 0, 0);
}

// ---------------- prep: transpose_cvt + wtrans(K,V) + Wq cvt + zero fused ------
// id [0,8192): transpose (b,c,n) f32 -> (b,n,c) bf16 for x and ctx
//              64x64 tiles, f32x4 global reads (G13), stride-65 LDS (2-way max,
//              free per m136), u16x8 coalesced stores.
// id [8192,8448): weight transpose (256,512) f32 -> (512,256) bf16 for Wk,Wv
// id [8448,8512): Wq (256,512) f32 -> bf16 copy (NO transpose; row-major in i)
// id [8512,9032): zero cm/ksum scratch
constexpr int ZERO_N = BATCH * 8 * 64 * 64 + BATCH * INNERD;  // 133120
__global__ __launch_bounds__(256) void prep(
    const float* __restrict__ x, const float* __restrict__ ctx,
    const float* __restrict__ Wk, const float* __restrict__ Wv,
    const float* __restrict__ Wq,
    u16* __restrict__ xt, u16* __restrict__ ct,
    u16* __restrict__ kt, u16* __restrict__ vt, u16* __restrict__ qc,
    float* __restrict__ zbuf) {
  __shared__ float tile[64][65];   // 16.6 KiB; reused by both transpose branches
  int id = blockIdx.x;
  int tid = threadIdx.x;
  if (id < 8192) {
    int bx = id & 255, by = (id >> 8) & 3, zb = id >> 10;   // 256 x 4 x 8
    int b = zb >> 1;
    const float* src = (zb & 1) ? ctx : x;
    u16* dst = (zb & 1) ? ct : xt;
    src += (size_t)b * CDIM * NTOK;
    dst += (size_t)b * NTOK * CDIM;
    int n0 = bx * 64, c0 = by * 64;
    int tx = tid & 15, ty = tid >> 4;       // tx: 16B col group; ty: 0..15
#pragma unroll
    for (int i = 0; i < 64; i += 16) {
      f32x4 v = *(const f32x4*)&src[(size_t)(c0 + ty + i) * NTOK + n0 + tx * 4];
#pragma unroll
      for (int j = 0; j < 4; j++) tile[ty + i][tx * 4 + j] = v[j];  // b32, 2-way max
    }
    __syncthreads();
    int nl = tid >> 3;              // 0..31
    int cl = (tid & 7) * 8;         // 0..56
#pragma unroll
    for (int j2 = 0; j2 < 2; j2++) {
      int nn = nl + 32 * j2;
      u16x8 o;
#pragma unroll
      for (int j = 0; j < 8; j++) o[j] = f2b(tile[cl + j][nn]);
      *(u16x8*)&dst[(size_t)(n0 + nn) * CDIM + c0 + cl] = o;
    }
  } else if (id < 8448) {
    int idw = id - 8192;
    int bx = idw & 15, by = (idw >> 4) & 7, bz = idw >> 7;  // 16 x 8 x 2
    float (*t2)[33] = (float(*)[33])tile;
    const float* src = bz == 0 ? Wk : Wv;
    u16* dst = bz == 0 ? kt : vt;
    int i0 = bx * 32, c0 = by * 32;
    int tx = tid & 31, ty = tid >> 5;
#pragma unroll
    for (int r = 0; r < 32; r += 8)
      t2[ty + r][tx] = src[(size_t)(c0 + ty + r) * INNERD + i0 + tx];
    __syncthreads();
#pragma unroll
    for (int r = 0; r < 32; r += 8)
      dst[(size_t)(i0 + ty + r) * CDIM + c0 + tx] = f2b(t2[tx][ty + r]);
  } else if (id < 8512) {
    // straight f32->bf16 copy of Wq: 131072 elems, 64 blocks x 256 thr x 8
    size_t off = (size_t)(id - 8448) * 2048 + tid * 8;
    f32x4 a = *(const f32x4*)&Wq[off];
    f32x4 c = *(const f32x4*)&Wq[off + 4];
    u16x8 o;
#pragma unroll
    for (int j = 0; j < 4; j++) { o[j] = f2b(a[j]); o[j + 4] = f2b(c[j]); }
    *(u16x8*)&qc[off] = o;
  } else {
    int i = (id - 8512) * 256 + tid;
    if (i < ZERO_N) zbuf[i] = 0.0f;
  }
}

// ================= fused projection + context matrix (prefetch ladder) =========
// Per block: b, i-range 128 (heads ig*2, ig*2+1), n-chunk 512.
// Sequential K->V (spill-free). BK=32 double-buffered staging, STAGE(next)
// before compute, one barrier per step. Verified 65 us config — do not touch.
__global__ __launch_bounds__(256, 2) void proj_ctx(
    const u16* __restrict__ Wkt, const u16* __restrict__ Wvt,
    const u16* __restrict__ ctx_bt, float* __restrict__ cm, float* __restrict__ ksum) {
  // 512 blocks = 4(ig) x 32(nc) x 4(b); chunked XCD swizzle
  int id = blockIdx.x;
  int swz = (id & 7) * 64 + (id >> 3);
  int ig = swz & 3, nc = (swz >> 2) & 31, b = swz >> 7;
  int i0 = ig * 128;
  const u16* Bt = ctx_bt + (size_t)b * NTOK * CDIM;

  __shared__ __align__(16) u16 smem[32768];   // 64 KiB -> 2 blocks/CU
  // staging buf p (p=0,1): A at p*8192, B at p*8192+4096 (each 128 rows x 32 k)
  u16* Ek = smem + 16384;    // [32K,64K) expK tile, dedicated
  u16* Vt = smem;            // [0,32K)   V tile, aliases both staging bufs

  int tid = threadIdx.x, wave = tid >> 6, lane = tid & 63;
  int wm = (wave >> 1) * 64, wn = (wave & 1) * 64;
  int quad = lane >> 4, l16 = lane & 15;
  int sr = lane >> 2, sc = (lane & 3) * 8;      // staging: 16 rows x 32 cols/chunk

  int hl = wave >> 1, dblk = (wave & 1) * 32;   // phase-2: wave -> (head, d-half)

  u16x8 ov;
#pragma unroll
  for (int t = 0; t < 8; t++) ov[t] = 0x3f80;   // bf16 1.0
  const bf16x8 ones = __builtin_bit_cast(bf16x8, ov);

  f32x4 acc_cm[2][4];
  f32x4 accS[2];
#pragma unroll
  for (int i = 0; i < 2; i++) {
    accS[i] = (f32x4)(0.0f);
#pragma unroll
    for (int j = 0; j < 4; j++) acc_cm[i][j] = (f32x4)(0.0f);
  }

  // stage step (kv, k-slice ks) into buf p. 16 chunks of 16rows x 32cols; 4/wave.
  auto stage = [&](int p, int kv, int ks, int n0) {
    int k0 = ks * 32;
    const u16* Asrc = kv ? Wvt : Wkt;
#pragma unroll
    for (int j = 0; j < 4; j++) {
      int c = wave * 4 + j;            // 0..15
      if (c < 8) {
        int row = c * 16 + sr;
        async_ld16(&Asrc[(size_t)(i0 + row) * CDIM + k0 + sc], &smem[p * 8192 + c * 512]);
      } else {
        int cb = c - 8, row = cb * 16 + sr;
        async_ld16(&Bt[(size_t)(n0 + row) * CDIM + k0 + sc], &smem[p * 8192 + 4096 + cb * 512]);
      }
    }
  };

  for (int nt = 0; nt < 4; nt++) {
    int n0 = nc * 512 + nt * 128;
    __syncthreads();                   // phase-2 reads of Vt/Ek done (or block start)
    stage(0, 0, 0, n0);
    __syncthreads();                   // buf0 ready (implicit vmcnt(0) drain)

    f32x4 acc[4][4];
#pragma unroll
    for (int i = 0; i < 4; i++)
#pragma unroll
      for (int j = 0; j < 4; j++) acc[i][j] = (f32x4)(0.0f);

#pragma unroll 2
    for (int s = 0; s < 16; s++) {     // s>>3 = kv, s&7 = k-slice
      int p = s & 1;
      if (s < 15) { int s1 = s + 1; stage(p ^ 1, s1 >> 3, s1 & 7, n0); }
      const u16* As = &smem[p * 8192];
      const u16* Bs = &smem[p * 8192 + 4096];
      bf16x8 af[4], bfr[4];
#pragma unroll
      for (int m = 0; m < 4; m++)
        af[m] = __builtin_bit_cast(bf16x8, *(const u16x8*)&As[(wm + m * 16 + l16) * 32 + quad * 8]);
#pragma unroll
      for (int e = 0; e < 4; e++)
        bfr[e] = __builtin_bit_cast(bf16x8, *(const u16x8*)&Bs[(wn + e * 16 + l16) * 32 + quad * 8]);
      // swapped operands: lane holds 4 consecutive n per frag
#pragma unroll
      for (int e = 0; e < 4; e++)
#pragma unroll
        for (int m = 0; m < 4; m++)
          acc[e][m] = __builtin_amdgcn_mfma_f32_16x16x32_bf16(bfr[e], af[m], acc[e][m], 0, 0, 0);

      if (s == 7) {
        // K-GEMM complete: write exp(K) to dedicated Ek (XOR-swz), reset acc for V
#pragma unroll
        for (int e = 0; e < 4; e++) {
          int nl0 = wn + e * 16 + quad * 4;
#pragma unroll
          for (int m = 0; m < 4; m++) {
            int row = wm + m * 16 + l16;
            u16x4 ok;
#pragma unroll
            for (int r = 0; r < 4; r++) ok[r] = f2b(__expf(acc[e][m][r]));
            unsigned byt = (unsigned)(row * 256 + nl0 * 2) ^ ((unsigned)(row & 7) << 4);
            *(u16x4*)((char*)Ek + byt) = ok;
            acc[e][m] = (f32x4)(0.0f);
          }
        }
      }
      __syncthreads();                 // next buf ready + buf-reuse safe
    }
    // acc holds V tile; staging fully drained & read -> Vt may alias it
#pragma unroll
    for (int e = 0; e < 4; e++) {
      int nl0 = wn + e * 16 + quad * 4;
#pragma unroll
      for (int m = 0; m < 4; m++) {
        int row = wm + m * 16 + l16;
        u16x4 ovv;
#pragma unroll
        for (int r = 0; r < 4; r++) ovv[r] = f2b(acc[e][m][r]);
        unsigned byt = (unsigned)(row * 256 + nl0 * 2) ^ ((unsigned)(row & 7) << 4);
        *(u16x4*)((char*)Vt + byt) = ovv;
      }
    }
    __syncthreads();                   // Ek/Vt visible to all waves
    // phase 2: per wave (hl, dblk): acc_cm[m2][e2] += Ek_row · Vt_row over 128 n
#pragma unroll
    for (int kk = 0; kk < 128; kk += 32) {
      int ko = kk + quad * 8;
      bf16x8 ea[2], vb[4];
#pragma unroll
      for (int m2 = 0; m2 < 2; m2++) {
        int row = hl * 64 + dblk + m2 * 16 + l16;
        unsigned byt = (unsigned)(row * 256 + ko * 2) ^ ((unsigned)(row & 7) << 4);
        ea[m2] = __builtin_bit_cast(bf16x8, *(const u16x8*)((char*)Ek + byt));
      }
#pragma unroll
      for (int e2 = 0; e2 < 4; e2++) {
        int row = hl * 64 + e2 * 16 + l16;
        unsigned byt = (unsigned)(row * 256 + ko * 2) ^ ((unsigned)(row & 7) << 4);
        vb[e2] = __builtin_bit_cast(bf16x8, *(const u16x8*)((char*)Vt + byt));
      }
#pragma unroll
      for (int m2 = 0; m2 < 2; m2++) {
        accS[m2] = __builtin_amdgcn_mfma_f32_16x16x32_bf16(ea[m2], ones, accS[m2], 0, 0, 0);
#pragma unroll
        for (int e2 = 0; e2 < 4; e2++)
          acc_cm[m2][e2] = __builtin_amdgcn_mfma_f32_16x16x32_bf16(ea[m2], vb[e2], acc_cm[m2][e2], 0, 0, 0);
      }
    }
    // next nt's first __syncthreads protects Ek/Vt vs staging overwrite
  }
  // epilogue: waves own disjoint (h, d-half) -> no intra-block contention
  int h = ig * 2 + hl;
  float* cmp = cm + (size_t)(b * 8 + h) * 64 * 64;
#pragma unroll
  for (int m2 = 0; m2 < 2; m2++)
#pragma unroll
    for (int e2 = 0; e2 < 4; e2++)
#pragma unroll
      for (int r = 0; r < 4; r++) {
        int d = dblk + m2 * 16 + quad * 4 + r;
        int e = e2 * 16 + l16;
        atomicAdd(&cmp[d * 64 + e], acc_cm[m2][e2][r]);
      }
  if (l16 == 0) {
#pragma unroll
    for (int m2 = 0; m2 < 2; m2++)
#pragma unroll
      for (int r = 0; r < 4; r++) {
        int d = dblk + m2 * 16 + quad * 4 + r;
        atomicAdd(&ksum[(size_t)b * INNERD + h * 64 + d], accS[m2][r]);
      }
  }
}

// ---------------- weff_t[b][c][i] = (sum_e cm[d][e]*Wo[h*64+e][c])/ksum (bf16) -
// TRANSPOSED + bf16 output so gt_k can stage it row-major-in-i via async_ld16.
__global__ __launch_bounds__(256) void weff_k(
    const float* __restrict__ cm, const float* __restrict__ Wo,
    const float* __restrict__ ksum, u16* __restrict__ weff_t) {
  int bi = blockIdx.x;            // 0..2047
  int b = bi >> 9, i = bi & 511, h = i >> 6, d = i & 63;
  const float* cmr = cm + ((size_t)(b * 8 + h) * 64 + d) * 64;
  __shared__ float cs[64];
  if (threadIdx.x < 64) cs[threadIdx.x] = cmr[threadIdx.x];
  __syncthreads();
  float inv = 1.0f / ksum[(size_t)b * INNERD + i];
  int c = threadIdx.x;
  float s = 0.0f;
#pragma unroll 8
  for (int e = 0; e < 64; e++) s += cs[e] * Wo[(size_t)(h * 64 + e) * CDIM + c];
  weff_t[((size_t)b * CDIM + c) * INNERD + i] = f2b(s * inv);
}

// ---------------- Gt[b][c][c'] = sum_i weff_t[b][c][i] * Wqc[c'][i]  (MFMA) ----
__global__ __launch_bounds__(256) void gt_k(
    const u16* __restrict__ weff_t, const u16* __restrict__ Wqc, u16* __restrict__ Gt) {
  int id = blockIdx.x;            // 16 = 2(x) * 2(y) * 4(b)
  int bx = id & 1, by = (id >> 1) & 1, b = id >> 2;
  const u16* A  = weff_t + (size_t)b * CDIM * INNERD;   // [c][512]
  const u16* Bt = Wqc;                                  // [c'][512]
  int i0 = bx * 128;              // c rows
  int n0 = by * 128;              // c' cols

  __shared__ __align__(16) u16 smem3[16384];   // 2 bufs x (A 4K + B 4K u16)

  int tid = threadIdx.x;
  int wave = tid >> 6, lane = tid & 63;
  int wm = (wave >> 1) * 64, wn = (wave & 1) * 64;
  int quad = lane >> 4, l16 = lane & 15;
  int sr = lane >> 2, sc = (lane & 3) * 8;

  auto stage = [&](int p, int ks) {
    int k0 = ks * 32;
#pragma unroll
    for (int j = 0; j < 4; j++) {
      int c = wave * 4 + j;
      if (c < 8) {
        int row = c * 16 + sr;
        async_ld16(&A[(size_t)(i0 + row) * INNERD + k0 + sc], &smem3[p * 8192 + c * 512]);
      } else {
        int cb = c - 8, row = cb * 16 + sr;
        async_ld16(&Bt[(size_t)(n0 + row) * INNERD + k0 + sc], &smem3[p * 8192 + 4096 + cb * 512]);
      }
    }
  };

  f32x4 acc[4][4];   // [e:c'-frag][m:c-frag]
#pragma unroll
  for (int i = 0; i < 4; i++)
#pragma unroll
    for (int j = 0; j < 4; j++) acc[i][j] = (f32x4)(0.0f);

  stage(0, 0);
  __syncthreads();
#pragma unroll 2
  for (int s = 0; s < 16; s++) {       // K=512 -> 16 BK=32 steps
    int p = s & 1;
    if (s < 15) stage(p ^ 1, s + 1);
    const u16* As = &smem3[p * 8192];
    const u16* Bs = &smem3[p * 8192 + 4096];
    bf16x8 af[4], bfr[4];
#pragma unroll
    for (int m = 0; m < 4; m++)
      af[m] = __builtin_bit_cast(bf16x8, *(const u16x8*)&As[(wm + m * 16 + l16) * 32 + quad * 8]);
#pragma unroll
    for (int e = 0; e < 4; e++)
      bfr[e] = __builtin_bit_cast(bf16x8, *(const u16x8*)&Bs[(wn + e * 16 + l16) * 32 + quad * 8]);
#pragma unroll
    for (int e = 0; e < 4; e++)
#pragma unroll
      for (int m = 0; m < 4; m++)
        acc[e][m] = __builtin_amdgcn_mfma_f32_16x16x32_bf16(bfr[e], af[m], acc[e][m], 0, 0, 0);
    if (s < 15) __syncthreads();
  }
  // lane's acc[e][m][r]: c = i0+wm+m*16+l16, c' = n0+wn+e*16+quad*4+r
#pragma unroll
  for (int e = 0; e < 4; e++) {
    int nb = n0 + wn + e * 16 + quad * 4;
#pragma unroll
    for (int m = 0; m < 4; m++) {
      int c = i0 + wm + m * 16 + l16;
      u16x4 o;
#pragma unroll
      for (int r = 0; r < 4; r++) o[r] = f2b(acc[e][m][r]);
      *(u16x4*)&Gt[((size_t)b * CDIM + c) * CDIM + nb] = o;
    }
  }
}

// ---------------- final: out[b][c][n] = x + bo[c] + sum_c' Gt[c][c'] x_bt[n][c']
// Prefetch ladder (BK=32, 8 steps); f32x4 residual epilogue.
__global__ __launch_bounds__(256) void final_gemm(
    const u16* __restrict__ Gt, const u16* __restrict__ x_bt,
    const float* __restrict__ x, const float* __restrict__ bo,
    float* __restrict__ out) {
  // flattened grid 1024 = 2(x) * 128(y) * 4(z); chunked XCD swizzle
  int id = blockIdx.x;
  int swz = (id & 7) * 128 + (id >> 3);
  int bx = swz & 1, by = (swz >> 1) & 127, b = swz >> 8;
  const u16* A  = Gt + (size_t)b * CDIM * CDIM;
  const u16* Bt = x_bt + (size_t)b * NTOK * CDIM;
  const float* xb = x + (size_t)b * CDIM * NTOK;
  float* ob = out + (size_t)b * CDIM * NTOK;
  int i0 = bx * 128;
  int n0 = by * 128;

  __shared__ __align__(16) u16 smem2[16384];   // 32 KiB: 2 bufs x (A 4K + B 4K u16)

  int tid = threadIdx.x;
  int wave = tid >> 6, lane = tid & 63;
  int wm = (wave >> 1) * 64, wn = (wave & 1) * 64;
  int quad = lane >> 4, l16 = lane & 15;
  int sr = lane >> 2, sc = (lane & 3) * 8;

  auto stage = [&](int p, int ks) {
    int k0 = ks * 32;
#pragma unroll
    for (int j = 0; j < 4; j++) {
      int c = wave * 4 + j;
      if (c < 8) {
        int row = c * 16 + sr;
        async_ld16(&A[(size_t)(i0 + row) * CDIM + k0 + sc], &smem2[p * 8192 + c * 512]);
      } else {
        int cb = c - 8, row = cb * 16 + sr;
        async_ld16(&Bt[(size_t)(n0 + row) * CDIM + k0 + sc], &smem2[p * 8192 + 4096 + cb * 512]);
      }
    }
  };

  f32x4 acc[4][4];   // [e:n-frag][m:c-frag]
#pragma unroll
  for (int i = 0; i < 4; i++)
#pragma unroll
    for (int j = 0; j < 4; j++) acc[i][j] = (f32x4)(0.0f);

  stage(0, 0);
  __syncthreads();
#pragma unroll 2
  for (int s = 0; s < 8; s++) {
    int p = s & 1;
    if (s < 7) stage(p ^ 1, s + 1);
    const u16* As = &smem2[p * 8192];
    const u16* Bs = &smem2[p * 8192 + 4096];
    bf16x8 af[4], bfr[4];
#pragma unroll
    for (int m = 0; m < 4; m++)
      af[m] = __builtin_bit_cast(bf16x8, *(const u16x8*)&As[(wm + m * 16 + l16) * 32 + quad * 8]);
#pragma unroll
    for (int e = 0; e < 4; e++)
      bfr[e] = __builtin_bit_cast(bf16x8, *(const u16x8*)&Bs[(wn + e * 16 + l16) * 32 + quad * 8]);
#pragma unroll
    for (int e = 0; e < 4; e++)
#pragma unroll
      for (int m = 0; m < 4; m++)
        acc[e][m] = __builtin_amdgcn_mfma_f32_16x16x32_bf16(bfr[e], af[m], acc[e][m], 0, 0, 0);
    if (s < 7) __syncthreads();
  }
  // lane's acc[e][m][r]: c = i0+wm+m*16+l16, n = n0+wn+e*16+quad*4+r
#pragma unroll
  for (int e = 0; e < 4; e++) {
    int nb = n0 + wn + e * 16 + quad * 4;
#pragma unroll
    for (int m = 0; m < 4; m++) {
      int c = i0 + wm + m * 16 + l16;
      f32x4 xv = *(const f32x4*)&xb[(size_t)c * NTOK + nb];
      f32x4 r;
      float bc = bo[c];
#pragma unroll
      for (int t = 0; t < 4; t++) r[t] = acc[e][m][t] + xv[t] + bc;
      *(f32x4*)&ob[(size_t)c * NTOK + nb] = r;
    }
  }
}

extern "C" void kernel_launch(void* const* d_in, const int* in_sizes, int n_in,
                              void* d_out, int out_size, void* d_ws, size_t ws_size,
                              hipStream_t stream) {
  const float* x   = (const float*)d_in[0];
  const float* ctx = (const float*)d_in[1];
  const float* Wq  = (const float*)d_in[2];
  const float* Wk  = (const float*)d_in[3];
  const float* Wv  = (const float*)d_in[4];
  const float* Wo  = (const float*)d_in[5];
  const float* bo  = (const float*)d_in[6];
  float* out = (float*)d_out;

  char* ws = (char*)d_ws;
  u16* ctx_bt = (u16*)ws;  ws += (size_t)BATCH * NTOK * CDIM * 2;     // 32 MiB
  u16* x_bt   = (u16*)ws;  ws += (size_t)BATCH * NTOK * CDIM * 2;     // 32 MiB
  u16* Wk_t   = (u16*)ws;  ws += (size_t)INNERD * CDIM * 2;
  u16* Wv_t   = (u16*)ws;  ws += (size_t)INNERD * CDIM * 2;
  u16* Wqc    = (u16*)ws;  ws += (size_t)CDIM * INNERD * 2;           // 256 KiB
  float* cm   = (float*)ws; ws += (size_t)BATCH * 8 * 64 * 64 * 4;    // 512 KiB
  float* ksum = (float*)ws; ws += (size_t)BATCH * INNERD * 4;         // 8 KiB (contiguous after cm)
  u16* weff_t = (u16*)ws;  ws += (size_t)BATCH * CDIM * INNERD * 2;   // 1 MiB
  u16* Gt     = (u16*)ws;  ws += (size_t)BATCH * CDIM * CDIM * 2;

  prep<<<dim3(9032), 256, 0, stream>>>(x, ctx, Wk, Wv, Wq, x_bt, ctx_bt,
                                       Wk_t, Wv_t, Wqc, cm /* zero cm+ksum */);
  proj_ctx<<<dim3(512), 256, 0, stream>>>(Wk_t, Wv_t, ctx_bt, cm, ksum);
  weff_k<<<BATCH * INNERD, 256, 0, stream>>>(cm, Wo, ksum, weff_t);
  gt_k<<<dim3(16), 256, 0, stream>>>(weff_t, Wqc, Gt);
  final_gemm<<<dim3(1024), 256, 0, stream>>>(Gt, x_bt, x, bo, out);
}